// Round 8
// baseline (188.059 us; speedup 1.0000x reference)
//
#include <hip/hip_runtime.h>

typedef __attribute__((ext_vector_type(4))) float  f32x4;
typedef __attribute__((ext_vector_type(8))) short  s16x8;
typedef __attribute__((ext_vector_type(4))) unsigned int u32x4;
typedef __attribute__((ext_vector_type(4))) unsigned short u16x4;

#define NB 8
#define NT 2048
#define NC 1024
#define NH 128
#define NM (NB * NT)

__device__ __forceinline__ unsigned short f2bf(float f) {
  union { float f; unsigned u; } v; v.f = f;
  unsigned r = v.u + 0x7FFFu + ((v.u >> 16) & 1u);  // RNE
  return (unsigned short)(r >> 16);
}
__device__ __forceinline__ unsigned pack2(float a, float b) {
  return (unsigned)f2bf(a) | ((unsigned)f2bf(b) << 16);
}
__device__ __forceinline__ f32x4 mfma16(s16x8 a, s16x8 b, f32x4 c) {
  return __builtin_amdgcn_mfma_f32_16x16x32_bf16(a, b, c, 0, 0, 0);
}

// ---------------- kernel 0: W -> bf16 transposed [3][128][1024], both sides coalesced
__global__ __launch_bounds__(256) void k_prep_w(
    const float* __restrict__ wq, const float* __restrict__ wk,
    const float* __restrict__ wv, unsigned short* __restrict__ wt3) {
  __shared__ float ts[64][65];
  const int tid = threadIdx.x;
  const int w = blockIdx.x >> 5;
  const int rem = blockIdx.x & 31;
  const int c0 = (rem >> 1) * 64;
  const int h0 = (rem & 1) * 64;
  const float* W = (w == 0) ? wq : (w == 1) ? wk : wv;
  const int hl = tid & 63, ci = tid >> 6;
  #pragma unroll
  for (int i = 0; i < 16; ++i) {
    int cl = i * 4 + ci;
    ts[cl][hl] = W[(size_t)(c0 + cl) * NH + h0 + hl];
  }
  __syncthreads();
  const int cl2 = tid & 63, hi2 = tid >> 6;
  #pragma unroll
  for (int j = 0; j < 16; ++j) {
    int hl2 = j * 4 + hi2;
    float v = ts[cl2][hl2];
    if (w == 0) v *= 0.08838834764831845f;
    wt3[(size_t)w * 131072 + (size_t)(h0 + hl2) * NC + c0 + cl2] = f2bf(v);
  }
}

// ---------------- kernel 1: q,k,v projections. BM=64, BN=192, BK=64; grid (256,2)
// = 512 blocks = 2 blocks/CU x 8 waves = 16 waves/CU. x prefetch DEPTH 2 (two
// ping-ponged reg sets -> 64B/thread in flight). W-frags from L2 per iter.
__global__ __launch_bounds__(512, 4) void k_qkv(
    const float* __restrict__ x, const unsigned short* __restrict__ wt3,
    unsigned short* __restrict__ qo, unsigned short* __restrict__ ko,
    unsigned short* __restrict__ vo) {
  __shared__ u32x4 xs4[16384 / 16];          // 2 bufs x [64 rows][128B bf16] swizzled
  char* xs = (char*)xs4;
  const int tid = threadIdx.x;
  const int lane = tid & 63;
  const int w = tid >> 6;                    // 0..7
  const int mg = w >> 2;                     // 0..1 (32-row m-half)
  const int ng = w & 3;                      // 0..3 (48-col n-strip)
  const int m0 = blockIdx.x * 64;
  const int n0 = blockIdx.y * 192 + ng * 48;
  const int c15 = lane & 15;
  const int g4 = lane >> 4;

  const int sr = tid >> 3;                   // staging row 0..63 (8 thr/row, 8 fp32 each)
  const float* xp = x + (size_t)(m0 + sr) * NC + (tid & 7) * 8;
  const int wb = (sr * 128 + (tid & 7) * 16) ^ ((sr & 7) << 4);

  f32x4 acc[2][3] = {};
  // two ping-ponged prefetch sets: setA = even tiles, setB = odd tiles
  f32x4 xA[2], xB[2];
  xA[0] = *(const f32x4*)(xp);          xA[1] = *(const f32x4*)(xp + 4);
  xB[0] = *(const f32x4*)(xp + 64);     xB[1] = *(const f32x4*)(xp + 68);
  {
    u32x4 pk = { pack2(xA[0].x, xA[0].y), pack2(xA[0].z, xA[0].w),
                 pack2(xA[1].x, xA[1].y), pack2(xA[1].z, xA[1].w) };
    *(u32x4*)(xs + wb) = pk;                 // buf0 <- tile0
  }
  __syncthreads();

  const int aswz = (c15 & 7) << 4;
  for (int kt = 0; kt < 16; ++kt) {
    // issue tile kt+2 into the set that held tile kt (already in LDS) — depth 2
    if (kt + 2 < 16) {
      f32x4* dst = (kt & 1) ? xB : xA;
      dst[0] = *(const f32x4*)(xp + (kt + 2) * 64);
      dst[1] = *(const f32x4*)(xp + (kt + 2) * 64 + 4);
    }
    s16x8 wf[2][3];                          // 6 L2 loads in flight
    {
      const unsigned short* wpb = wt3 + (size_t)(n0 + c15) * NC + kt * 64 + g4 * 8;
      #pragma unroll
      for (int ks = 0; ks < 2; ++ks)
        #pragma unroll
        for (int nj = 0; nj < 3; ++nj)
          wf[ks][nj] = *(const s16x8*)(wpb + (size_t)nj * 16 * NC + ks * 32);
    }
    char* cb = xs + (kt & 1) * 8192;
    #pragma unroll
    for (int ks = 0; ks < 2; ++ks) {
      #pragma unroll
      for (int mf = 0; mf < 2; ++mf) {
        int arow = mg * 32 + mf * 16 + c15;
        s16x8 af = *(const s16x8*)(cb + ((arow * 128 + ks * 64 + g4 * 16) ^ aswz));
        #pragma unroll
        for (int nj = 0; nj < 3; ++nj)
          acc[mf][nj] = mfma16(af, wf[ks][nj], acc[mf][nj]);
      }
    }
    if (kt + 1 < 16) {                       // write tile kt+1 (issued 1-2 iters ago)
      f32x4* srcp = ((kt + 1) & 1) ? xB : xA;
      u32x4 pk = { pack2(srcp[0].x, srcp[0].y), pack2(srcp[0].z, srcp[0].w),
                   pack2(srcp[1].x, srcp[1].y), pack2(srcp[1].z, srcp[1].w) };
      *(u32x4*)(xs + ((kt + 1) & 1) * 8192 + wb) = pk;
    }
    __syncthreads();
  }
  // epilogue: q,k row-major [M][128]; v transposed [B][128][T]
  #pragma unroll
  for (int mf = 0; mf < 2; ++mf) {
    #pragma unroll
    for (int nj = 0; nj < 3; ++nj) {
      f32x4 a = acc[mf][nj];
      int gcol = n0 + nj * 16 + c15;
      int gr = m0 + mg * 32 + mf * 16 + g4 * 4;
      int h = gcol & 127;
      if (gcol < 256) {
        unsigned short* dst = (gcol < 128) ? qo : ko;
        dst[(size_t)(gr + 0) * NH + h] = f2bf(a.x);
        dst[(size_t)(gr + 1) * NH + h] = f2bf(a.y);
        dst[(size_t)(gr + 2) * NH + h] = f2bf(a.z);
        dst[(size_t)(gr + 3) * NH + h] = f2bf(a.w);
      } else {
        int bb = gr >> 11, tt = gr & 2047;
        u16x4 pv = { f2bf(a.x), f2bf(a.y), f2bf(a.z), f2bf(a.w) };
        *(u16x4*)(vo + ((size_t)(bb * NH + h) * NT + tt)) = pv;
      }
    }
  }
}

// ---------------- kernel 2: flash attention. QBLK=64, kv-split x2, KVBLK=128.
// (unchanged — frozen until its counters appear; becomes top-1 next round)
__global__ __launch_bounds__(512, 2) void k_attn(
    const unsigned short* __restrict__ qg, const unsigned short* __restrict__ kg,
    const unsigned short* __restrict__ vg, float* __restrict__ out) {
  __shared__ u32x4 lds4[147456 / 16];        // 144KB
  char* L = (char*)lds4;
  const int tid = threadIdx.x;
  const int lane = tid & 63;
  const int w = tid >> 6;                    // 0..7
  const int grp = w & 1;                     // kv half
  const int qs = w >> 1;                     // q sub-tile (16 rows)
  const int gl = qs * 64 + lane;             // group-local 0..255
  const int b = blockIdx.y;
  const int qr0 = blockIdx.x * 64;
  const int c15 = lane & 15;
  const int g4 = lane >> 4;
  const int kv0 = grp * 1024;

  char* Kg = L + grp * 65536;                // [128 kv][256B] swizzled (32KB)
  char* Vg = Kg + 32768;                     // [128 h][256B kv] swizzled (32KB)
  char* pw = L + 131072 + w * 2048;          // per-wave P [16 q][64 kv] swizzled

  s16x8 qf[4];
  #pragma unroll
  for (int ks = 0; ks < 4; ++ks)
    qf[ks] = *(const s16x8*)(qg + (size_t)(b * NT + qr0 + qs * 16 + c15) * NH + ks * 32 + g4 * 8);

  float m_run[4], lsum[4];
  #pragma unroll
  for (int r = 0; r < 4; ++r) { m_run[r] = -3.0e38f; lsum[r] = 0.0f; }
  f32x4 acc_o[8] = {};

  const int srow = gl >> 4;                  // 0..15 (+16i)
  const unsigned short* kptr = kg + (size_t)(b * NT + kv0 + srow) * NH + (gl & 15) * 8;
  const unsigned short* vptr = vg + (size_t)(b * NH + srow) * NT + kv0 + (gl & 15) * 8;

  u32x4 kreg[8], vreg[8];
  auto stage = [&](int kt) {
    #pragma unroll
    for (int i = 0; i < 8; ++i) {
      kreg[i] = *(const u32x4*)(kptr + ((size_t)(kt * 128 + i * 16)) * NH);
      vreg[i] = *(const u32x4*)(vptr + (size_t)(i * 16) * NT + kt * 128);
    }
  };
  auto write_tiles = [&]() {
    #pragma unroll
    for (int i = 0; i < 8; ++i) {
      int r = srow + i * 16;
      int off = (r * 256 + (gl & 15) * 16) ^ ((r & 7) << 4);
      *(u32x4*)(Kg + off) = kreg[i];
      *(u32x4*)(Vg + off) = vreg[i];
    }
  };
  stage(0);
  write_tiles();
  __syncthreads();

  for (int kt = 0; kt < 8; ++kt) {
    if (kt < 7) stage(kt + 1);               // 16x16B in flight across compute
    // S = Q K^T -> [16 q][128 kv]
    f32x4 s[8];
    __builtin_amdgcn_s_setprio(1);
    #pragma unroll
    for (int nj = 0; nj < 8; ++nj) {
      f32x4 acc_s = {};
      int kr = nj * 16 + c15;
      int kswz = (kr & 7) << 4;
      #pragma unroll
      for (int ks = 0; ks < 4; ++ks) {
        s16x8 bf = *(const s16x8*)(Kg + ((kr * 256 + ks * 64 + g4 * 16) ^ kswz));
        acc_s = mfma16(qf[ks], bf, acc_s);
      }
      s[nj] = acc_s;
    }
    __builtin_amdgcn_s_setprio(0);
    // online softmax (row in 16-lane group), deferred l
    float alpha[4];
    #pragma unroll
    for (int r = 0; r < 4; ++r) {
      float pm = fmaxf(fmaxf(fmaxf(s[0][r], s[1][r]), fmaxf(s[2][r], s[3][r])),
                       fmaxf(fmaxf(s[4][r], s[5][r]), fmaxf(s[6][r], s[7][r])));
      pm = fmaxf(pm, __shfl_xor(pm, 1));
      pm = fmaxf(pm, __shfl_xor(pm, 2));
      pm = fmaxf(pm, __shfl_xor(pm, 4));
      pm = fmaxf(pm, __shfl_xor(pm, 8));
      float mn = fmaxf(m_run[r], pm);
      alpha[r] = __expf(m_run[r] - mn);
      m_run[r] = mn;
      float psum = 0.0f;
      #pragma unroll
      for (int nj = 0; nj < 8; ++nj) {
        float e = __expf(s[nj][r] - mn);
        s[nj][r] = e;
        psum += e;
      }
      lsum[r] = lsum[r] * alpha[r] + psum;
    }
    #pragma unroll
    for (int hj = 0; hj < 8; ++hj) {
      acc_o[hj][0] *= alpha[0]; acc_o[hj][1] *= alpha[1];
      acc_o[hj][2] *= alpha[2]; acc_o[hj][3] *= alpha[3];
    }
    // two P halves of 64 kv each; P write is wave-local (no barrier)
    #pragma unroll
    for (int half = 0; half < 2; ++half) {
      #pragma unroll
      for (int nj = 0; nj < 4; ++nj) {
        #pragma unroll
        for (int r = 0; r < 4; ++r) {
          int row = g4 * 4 + r;
          *(unsigned short*)(pw + ((row * 128 + (nj * 16 + c15) * 2) ^ ((row & 7) << 4)))
              = f2bf(s[half * 4 + nj][r]);
        }
      }
      __builtin_amdgcn_s_setprio(1);
      #pragma unroll
      for (int ks2 = 0; ks2 < 2; ++ks2) {
        s16x8 pa = *(const s16x8*)(pw + ((c15 * 128 + ks2 * 64 + g4 * 16) ^ ((c15 & 7) << 4)));
        int vcb = (half * 2 + ks2) * 64 + g4 * 16;
        #pragma unroll
        for (int hj = 0; hj < 8; ++hj) {
          int vr = hj * 16 + c15;
          s16x8 bv = *(const s16x8*)(Vg + ((vr * 256 + vcb) ^ ((vr & 7) << 4)));
          acc_o[hj] = mfma16(pa, bv, acc_o[hj]);
        }
      }
      __builtin_amdgcn_s_setprio(0);
    }
    __syncthreads();                         // all waves done with K/V
    if (kt < 7) write_tiles();               // vmcnt wait (covered by compute)
    __syncthreads();
  }
  // finish deferred l
  float l_run[4];
  #pragma unroll
  for (int r = 0; r < 4; ++r) {
    float ls = lsum[r];
    ls += __shfl_xor(ls, 1);
    ls += __shfl_xor(ls, 2);
    ls += __shfl_xor(ls, 4);
    ls += __shfl_xor(ls, 8);
    l_run[r] = ls;
  }
  // 2-way merge through LDS
  float* msh = (float*)(L + 131072);         // 64 rows
  float* lsh = msh + 64;
  if (grp == 1) {
    #pragma unroll
    for (int r = 0; r < 4; ++r) {
      int row = qs * 16 + g4 * 4 + r;
      #pragma unroll
      for (int hj = 0; hj < 8; ++hj)
        *(float*)(L + row * 512 + (hj * 16 + c15) * 4) = acc_o[hj][r];
      if (c15 == 0) { msh[row] = m_run[r]; lsh[row] = l_run[r]; }
    }
  }
  __syncthreads();
  if (grp == 0) {
    #pragma unroll
    for (int r = 0; r < 4; ++r) {
      int row = qs * 16 + g4 * 4 + r;
      float m1 = msh[row], l1 = lsh[row];
      float M = fmaxf(m_run[r], m1);
      float w0 = __expf(m_run[r] - M);
      float w1 = __expf(m1 - M);
      float den = 1.0f / (w0 * l_run[r] + w1 * l1);
      #pragma unroll
      for (int hj = 0; hj < 8; ++hj) {
        float o1 = *(const float*)(L + row * 512 + (hj * 16 + c15) * 4);
        out[(size_t)(b * NT + qr0 + row) * NH + hj * 16 + c15] =
            (w0 * acc_o[hj][r] + w1 * o1) * den;
      }
    }
  }
}

extern "C" void kernel_launch(void* const* d_in, const int* in_sizes, int n_in,
                              void* d_out, int out_size, void* d_ws, size_t ws_size,
                              hipStream_t stream) {
  const float* x  = (const float*)d_in[0];
  const float* wq = (const float*)d_in[1];
  const float* wk = (const float*)d_in[2];
  const float* wv = (const float*)d_in[3];
  unsigned short* ws  = (unsigned short*)d_ws;
  unsigned short* qb  = ws;                           // [M][128] bf16   (4MB)
  unsigned short* kb  = ws + (size_t)2 * 1024 * 1024; // [M][128] bf16   (4MB)
  unsigned short* vb  = ws + (size_t)4 * 1024 * 1024; // [B][128][T] bf16 (4MB)
  unsigned short* wt3 = ws + (size_t)6 * 1024 * 1024; // [3][128][1024] bf16 (0.75MB)

  k_prep_w<<<dim3(96), dim3(256), 0, stream>>>(wq, wk, wv, wt3);
  k_qkv<<<dim3(256, 2), dim3(512), 0, stream>>>(x, wt3, qb, kb, vb);
  k_attn<<<dim3(NT / 64, NB), dim3(512), 0, stream>>>(qb, kb, vb, (float*)d_out);
}